// Round 6
// baseline (357.913 us; speedup 1.0000x reference)
//
#include <hip/hip_runtime.h>
#include <math.h>

#define S 512
#define B 128
#define T 256
#define NTH 512
#define LOG2E 1.44269504f
#define LN2 0.69314718f

typedef _Float16 h2 __attribute__((ext_vector_type(2)));

#if __has_builtin(__builtin_amdgcn_fdot2)
#define FDOT2(a, b, c) __builtin_amdgcn_fdot2((a), (b), (c), false)
#else
#define FDOT2(a, b, c) fmaf((float)(a)[0], (float)(b)[0], fmaf((float)(a)[1], (float)(b)[1], (c)))
#endif

#if __has_builtin(__builtin_amdgcn_exp2f)
#define EXP2(x) __builtin_amdgcn_exp2f(x)
#else
#define EXP2(x) exp2f(x)
#endif
#if __has_builtin(__builtin_amdgcn_logf)
#define LOG2(x) __builtin_amdgcn_logf(x)
#else
#define LOG2(x) __log2f(x)
#endif

// cvt_pkrtz returns __fp16 vector; bit_cast to our h2
#define PKRTZ(a, b) __builtin_bit_cast(h2, __builtin_amdgcn_cvt_pkrtz((a), (b)))

#define AS1 __attribute__((address_space(1)))
#define AS3 __attribute__((address_space(3)))

// LDS-drain barrier only (DMA ring stays in flight; counted vmcnt elsewhere)
#define BAR() do { asm volatile("s_waitcnt lgkmcnt(0)" ::: "memory"); __builtin_amdgcn_s_barrier(); } while (0)

// exact x * 2^n (n in [-126,127])
__device__ __forceinline__ float mul2n(float x, int n) {
    return x * __builtin_bit_cast(float, (n + 127) << 23);
}

template<int CTRL, int RM>
__device__ __forceinline__ float dppmax(float x) {
    int xi = __builtin_bit_cast(int, x);
    int yi = __builtin_amdgcn_update_dpp(xi, xi, CTRL, RM, 0xf, false);
    return fmaxf(x, __builtin_bit_cast(float, yi));
}
// full 64-lane max, result broadcast
__device__ __forceinline__ float wave_max64(float x) {
    x = dppmax<0x111, 0xf>(x);
    x = dppmax<0x112, 0xf>(x);
    x = dppmax<0x114, 0xf>(x);
    x = dppmax<0x118, 0xf>(x);
    x = dppmax<0x142, 0xa>(x);  // row_bcast:15
    x = dppmax<0x143, 0xc>(x);  // row_bcast:31
    return __builtin_bit_cast(float, __builtin_amdgcn_readlane(__builtin_bit_cast(int, x), 63));
}
// max over lanes 0..31 (call under exec mask lane<32), result broadcast
__device__ __forceinline__ float wave_max32(float x) {
    x = dppmax<0x111, 0xf>(x);
    x = dppmax<0x112, 0xf>(x);
    x = dppmax<0x114, 0xf>(x);
    x = dppmax<0x118, 0xf>(x);
    x = dppmax<0x142, 0xa>(x);  // row_bcast:15 -> lane31 = max(0..31)
    return __builtin_bit_cast(float, __builtin_amdgcn_readlane(__builtin_bit_cast(int, x), 31));
}
// lane gets lane|1's value within each quad
__device__ __forceinline__ float quad_next(float x) {
    int xi = __builtin_bit_cast(int, x);
    int yi = __builtin_amdgcn_update_dpp(xi, xi, 0xF5, 0xf, 0xf, false);
    return __builtin_bit_cast(float, yi);
}

__global__ __launch_bounds__(NTH, 1) void crf_fwd(
    const float* __restrict__ feats,
    const int*   __restrict__ tags,
    const int*   __restrict__ mask,
    const float* __restrict__ start_t,
    const float* __restrict__ end_t,
    const float* __restrict__ trans,
    float*       __restrict__ out)
{
    const int b    = blockIdx.x;
    const int tid  = threadIdx.x;
    const int lane = tid & 63;
    const int w    = tid >> 6;        // wave 0..7: GEMV rows [32w,32w+32), combine cols 32w+lane (lane<32)

    __shared__ float part[2][8][T];                               // 16 KB, ping-pong
    __shared__ float ftile[8][T];                                 // 8 KB DMA ring (prefetch dist 3)
    __shared__ int   msk[S];
    __shared__ float scf[T];
    __shared__ float ef[T];
    __shared__ __attribute__((aligned(16))) float redq[2][8];
    __shared__ float redg[8], redm[8], redi[8];

    // ---- prime DMA ring: tiles 1..3 (threads 0..255 = waves 0-3)
    if (tid < T) {
        #pragma unroll
        for (int tn = 1; tn <= 3; ++tn) {
            const float* src = feats + ((size_t)tn * B + b) * T + tid;
            __builtin_amdgcn_global_load_lds((const AS1 void*)src,
                                             (AS3 void*)&ftile[tn][tid], 4, 0, 0);
        }
    }

    // ---- init loads
    msk[tid] = mask[tid * B + b];     // tid covers S=512 exactly
    float sc0 = -3.0e38f;
    if (tid < T) {
        sc0 = start_t[tid] + feats[(size_t)b * T + tid];
        scf[tid] = sc0;
        ef[tid]  = end_t[tid];
    }

    // ---- gold-score terms: one time step per thread (512 = S)
    float gterm = 0.f, mcnt = 0.f;
    {
        const int t  = tid;
        const int tg = tags[t * B + b];
        const int m  = mask[t * B + b];
        const float emit = feats[((size_t)t * B + b) * T + tg];
        mcnt = (float)m;
        if (t == 0) gterm = start_t[tg] + emit;
        else        gterm = m ? (emit + trans[tags[(t - 1) * B + b] * T + tg]) : 0.f;
    }
    #pragma unroll
    for (int o = 32; o > 0; o >>= 1) {
        gterm += __shfl_down(gterm, o, 64);
        mcnt  += __shfl_down(mcnt, o, 64);
    }
    if (lane == 0) { redg[w] = gterm; redm[w] = mcnt; }

    // ---- init max of sc0 (waves 0-3 hold it)
    {
        const float mx = wave_max64(sc0);
        if (lane == 0 && w < 4) redi[w] = mx;
    }

    // ---- E fragment: rows [32w,32w+32), cols 4*lane..+3; pairs over rows
    h2 E2[16][4];
    {
        const float* tp = trans + (size_t)(32 * w) * T + 4 * lane;
        #pragma unroll
        for (int ip = 0; ip < 16; ++ip) {
            const float4 ra = *(const float4*)(tp + (size_t)(2 * ip) * T);
            const float4 rb = *(const float4*)(tp + (size_t)(2 * ip + 1) * T);
            #pragma unroll
            for (int c = 0; c < 4; ++c) {
                const float e0 = EXP2(LOG2E * (c == 0 ? ra.x : c == 1 ? ra.y : c == 2 ? ra.z : ra.w));
                const float e1 = EXP2(LOG2E * (c == 0 ? rb.x : c == 1 ? rb.y : c == 2 ? rb.z : rb.w));
                h2 v; v[0] = (_Float16)e0; v[1] = (_Float16)e1;
                E2[ip][c] = v;
            }
        }
    }

    __syncthreads();   // init: scf/redi/redg/redm visible (full drain once)

    float gold = 0.f;
    if (tid == 0) {
        float g = 0.f, mc = 0.f;
        #pragma unroll
        for (int k8 = 0; k8 < 8; ++k8) { g += redg[k8]; mc += redm[k8]; }
        gold = g + end_t[tags[((int)mc - 1) * B + b]];
    }

    // ---- linear-state init: q = 2^(sc0*log2e - A), global A so max(q) ~= 2^-10
    const float gmax0 = fmaxf(fmaxf(redi[0], redi[1]), fmaxf(redi[2], redi[3]));
    int A = (int)ceilf(gmax0 * LOG2E) + 10;
    float q = 0.f;
    int pki = 0;
    if (lane < 32) {
        q = EXP2(fmaf(scf[32 * w + lane], LOG2E, (float)(-A)));
        const float m32 = wave_max32(q);
        if (lane == 0) redq[0][w] = m32;
        pki = __builtin_bit_cast(int, PKRTZ(q, quad_next(q)));
    }
    __syncthreads();   // redq[0] + pki states settled before first loop epoch

    for (int t = 1; t < S; ++t) {
        // ---- GEMV: rows [32w,32w+32) x 256 cols; q pairs via readlane of own lanes
        float a0 = 0.f, a1 = 0.f, a2 = 0.f, a3 = 0.f;
        int pr = __builtin_amdgcn_readlane(pki, 0);
        #pragma unroll
        for (int ip = 0; ip < 16; ++ip) {
            const int prn = (ip < 15) ? __builtin_amdgcn_readlane(pki, 2 * ip + 2) : 0;
            const h2 pp = __builtin_bit_cast(h2, pr);
            a0 = FDOT2(E2[ip][0], pp, a0);
            a1 = FDOT2(E2[ip][1], pp, a1);
            a2 = FDOT2(E2[ip][2], pp, a2);
            a3 = FDOT2(E2[ip][3], pp, a3);
            pr = prn;
        }
        {
            float4 acc; acc.x = a0; acc.y = a1; acc.z = a2; acc.w = a3;
            *(float4*)&part[t & 1][w][4 * lane] = acc;
        }
        // ---- DMA ring (waves 0-3): prefetch tile t+3 into 8-slot ring
        if (tid < T) {
            if (t < S - 3) {
                const float* src = feats + ((size_t)(t + 3) * B + b) * T + tid;
                __builtin_amdgcn_global_load_lds((const AS1 void*)src,
                                                 (AS3 void*)&ftile[(t + 3) & 7][tid], 4, 0, 0);
                asm volatile("s_waitcnt vmcnt(3)" ::: "memory");   // tile t landed
            } else {
                asm volatile("s_waitcnt vmcnt(0)" ::: "memory");
            }
        }
        BAR();   // the only barrier per step

        // ---- combine (lanes 0-31; col c = 32w+lane): plain 8-way add, global scale
        const int mskt = msk[t];
        if (lane < 32) {
            const int c = 32 * w + lane;
            const float4 rqa = *(const float4*)&redq[(t - 1) & 1][0];
            const float4 rqb = *(const float4*)&redq[(t - 1) & 1][4];
            const float p0 = part[t & 1][0][c];
            const float p1 = part[t & 1][1][c];
            const float p2 = part[t & 1][2][c];
            const float p3 = part[t & 1][3][c];
            const float p4 = part[t & 1][4][c];
            const float p5 = part[t & 1][5][c];
            const float p6 = part[t & 1][6][c];
            const float p7 = part[t & 1][7][c];
            const float ft = ftile[t & 7][c];
            const float gm = fmaxf(fmaxf(fmaxf(rqa.x, rqa.y), fmaxf(rqa.z, rqa.w)),
                                   fmaxf(fmaxf(rqb.x, rqb.y), fmaxf(rqb.z, rqb.w)));
            const int k = ((__builtin_bit_cast(int, gm) >> 23) & 0xff) - 117;  // exp(gm)-127+10
            const float cb = ((p0 + p1) + (p2 + p3)) + ((p4 + p5) + (p6 + p7));
            const float F  = EXP2(fmaf(ft, LOG2E, (float)(-k)));   // exp(ft)*2^-k
            const float qn = cb * F;
            const float qf = mul2n(q, -k);                          // frozen path
            q = mskt ? qn : qf;
            A += k;
            const float m32 = wave_max32(q);
            if (lane == 0) redq[t & 1][w] = m32;
            pki = __builtin_bit_cast(int, PKRTZ(q, quad_next(q)));
        }
    }

    BAR();

    // ---- finalize: score_c = (log2 q + A)*ln2; forward = LSE(score + end)
    float u2 = -3.0e38f;
    if (lane < 32) u2 = LOG2(q) + (float)A + ef[32 * w + lane] * LOG2E;
    {
        const float mw = wave_max64(u2);          // upper lanes -inf-ish
        if (lane == 0) redq[0][w] = mw;
    }
    BAR();
    {
        const float gmax = fmaxf(
            fmaxf(fmaxf(redq[0][0], redq[0][1]), fmaxf(redq[0][2], redq[0][3])),
            fmaxf(fmaxf(redq[0][4], redq[0][5]), fmaxf(redq[0][6], redq[0][7])));
        float e = (lane < 32) ? EXP2(u2 - gmax) : 0.f;
        #pragma unroll
        for (int o = 32; o > 0; o >>= 1) e += __shfl_xor(e, o, 64);
        if (lane == 0) redg[w] = e;
        BAR();
        if (tid == 0) {
            float ssum = 0.f;
            #pragma unroll
            for (int k8 = 0; k8 < 8; ++k8) ssum += redg[k8];
            out[b] = (gmax + LOG2(ssum)) * LN2 - gold;
        }
    }
}

extern "C" void kernel_launch(void* const* d_in, const int* in_sizes, int n_in,
                              void* d_out, int out_size, void* d_ws, size_t ws_size,
                              hipStream_t stream) {
    const float* feats  = (const float*)d_in[0];
    const int*   tags   = (const int*)d_in[1];
    const int*   mask   = (const int*)d_in[2];
    const float* startt = (const float*)d_in[3];
    const float* endt   = (const float*)d_in[4];
    const float* transt = (const float*)d_in[5];
    float* out = (float*)d_out;
    crf_fwd<<<dim3(B), dim3(NTH), 0, stream>>>(feats, tags, mask, startt, endt, transt, out);
}